// Round 2
// baseline (680.198 us; speedup 1.0000x reference)
//
#include <hip/hip_runtime.h>
#include <hip/hip_bf16.h>

typedef __hip_bfloat16 bf16;
typedef __attribute__((ext_vector_type(8))) __bf16 bf16x8;
typedef __attribute__((ext_vector_type(4))) float f32x4;
typedef unsigned int u32;

#define HW 16384

static __device__ __forceinline__ float b2f(bf16 v) { return __bfloat162float(v); }
static __device__ __forceinline__ bf16 f2b(float v) { return __float2bfloat16(v); }
static __device__ __forceinline__ float blo(unsigned int w) {
    return __uint_as_float(w << 16);
}
static __device__ __forceinline__ float bhi(unsigned int w) {
    return __uint_as_float(w & 0xffff0000u);
}
static __device__ __forceinline__ unsigned short f2bu(float v) {
    union { bf16 b; unsigned short u; } c; c.b = f2b(v); return c.u;
}

static __device__ __forceinline__ void stf(float* p, float v) { *p = v; }
static __device__ __forceinline__ void stf(bf16* p, float v)  { *p = f2b(v); }

// load 8 consecutive values as f32 (16B- or 32B-vectorized)
static __device__ __forceinline__ void load8(const float* p, float* v) {
    const float4* q = (const float4*)p;
    float4 a = q[0], b = q[1];
    v[0] = a.x; v[1] = a.y; v[2] = a.z; v[3] = a.w;
    v[4] = b.x; v[5] = b.y; v[6] = b.z; v[7] = b.w;
}
static __device__ __forceinline__ void load8(const bf16* p, float* v) {
    uint4 u = *(const uint4*)p;
    v[0] = blo(u.x); v[1] = bhi(u.x); v[2] = blo(u.y); v[3] = bhi(u.y);
    v[4] = blo(u.z); v[5] = bhi(u.z); v[6] = blo(u.w); v[7] = bhi(u.w);
}

// ============ K1/K7: MFMA GEMM Y[b] = W(MxK=192,f32) @ X[b](192xN) ==========
// Register-resident A (whole K=192 per wave: 12 bf16x8 = 48 VGPR), whole-K
// B slab staged once per 64-column n-tile into a conflict-free XOR layout:
//   Bs[n][slot][8k], slot = kb ^ (n>>3), row = 512 B (bank-period aligned).
//   - ds_write_b128: 8 writers sharing kb have noct=n>>3 = 0..7 -> 8 distinct
//     slots -> 8 distinct bank groups -> conflict-free.
//   - ds_read_b128: (quad, n>>3) spread kb^nb over 8 bank groups -> free.
// One raw-barrier pair per n-tile (was 12 syncthreads per tile); next tile's
// global loads issued between ds_writes and compute -> HBM latency hidden
// under 24 MFMAs (T14). MFMA order identical to previous version -> bitwise
// same output. Grid: blockIdx%8 = XCD = batch; m-fastest within 512-col
// n-group -> the MB blocks sharing an X panel co-resident on one L2.
template <typename TX, typename TY>
__global__ __launch_bounds__(256) void gemm_mfma(
    const float* __restrict__ Wm, const TX* __restrict__ X,
    TY* __restrict__ Y, int MB)
{
    constexpr int K = 192, N = HW, T = 8;
    constexpr int NPF = (sizeof(TX) == 4) ? 16 : 8;

    const int b    = blockIdx.x & 7;      // XCD-chunk: batch per XCD
    const int slot = blockIdx.x >> 3;
    const int mb   = slot % MB;           // m fastest -> panel sharing on L2
    const int g    = slot / MB;           // n-group of 512 columns
    const int m0   = mb * 64;

    const TX* Xb = X + (size_t)b * K * N;
    TY* Yb = Y + (size_t)b * (MB * 64) * N;

    __shared__ __bf16 Bs[64][256];   // 64 n-rows x 512 B (32 slots x 16 B)

    const int tid  = threadIdx.x;
    const int lane = tid & 63, wave = tid >> 6;
    const int wm = (wave & 1) * 32, wn = (wave >> 1) * 32;
    const int r16 = lane & 15, quad = lane >> 4;

    // ---- A (weights) -> registers, once per block ----
    bf16x8 aReg[6][2];
#pragma unroll
    for (int ks = 0; ks < 6; ks++)
#pragma unroll
        for (int h = 0; h < 2; h++) {
            const float* ap = Wm + (size_t)(m0 + wm + h * 16 + r16) * K
                            + ks * 32 + quad * 8;
            float4 f0 = ((const float4*)ap)[0];
            float4 f1 = ((const float4*)ap)[1];
            bf16x8 fr;
            fr[0] = (__bf16)f0.x; fr[1] = (__bf16)f0.y;
            fr[2] = (__bf16)f0.z; fr[3] = (__bf16)f0.w;
            fr[4] = (__bf16)f1.x; fr[5] = (__bf16)f1.y;
            fr[6] = (__bf16)f1.z; fr[7] = (__bf16)f1.w;
            aReg[ks][h] = fr;
        }

    // staging role: thread -> (kb = 8-k-row block 0..23, noct = 8-n block 0..7)
    const int kb   = tid >> 3;           // active if < 24 (waves 0..2)
    const int noct = tid & 7;
    const bool act = (kb < 24);

    uint4 pf[NPF];

    auto load_tile = [&](int t) {
        if (!act) return;
        const TX* src = Xb + (size_t)(kb * 8) * N + g * 512 + t * 64 + noct * 8;
#pragma unroll
        for (int j = 0; j < 8; j++) {
            if constexpr (sizeof(TX) == 4) {
                const uint4* s = (const uint4*)(src + (size_t)j * N);
                pf[2 * j]     = s[0];
                pf[2 * j + 1] = s[1];
            } else {
                pf[j] = *(const uint4*)(src + (size_t)j * N);
            }
        }
    };

    auto write_tile = [&]() {
        if (!act) return;
        char* dst = (char*)Bs + (size_t)(noct * 8) * 512 + ((kb ^ noct) << 4);
#pragma unroll
        for (int jn = 0; jn < 8; jn++) {
            u32 w[4];
#pragma unroll
            for (int wd = 0; wd < 4; wd++) {
                if constexpr (sizeof(TX) == 4) {
                    // rows 2wd, 2wd+1; row r spans pf[2r], pf[2r+1]
                    float f0 = ((const float*)&pf[4 * wd + (jn >> 2)])[jn & 3];
                    float f1 = ((const float*)&pf[4 * wd + 2 + (jn >> 2)])[jn & 3];
                    w[wd] = (u32)f2bu(f0) | ((u32)f2bu(f1) << 16);
                } else {
                    u32 a = ((const u32*)&pf[2 * wd])[jn >> 1];
                    u32 c = ((const u32*)&pf[2 * wd + 1])[jn >> 1];
                    w[wd] = (jn & 1) ? ((a >> 16) | (c & 0xffff0000u))
                                     : ((a & 0xffffu) | (c << 16));
                }
            }
            *(uint4*)(dst + jn * 512) = make_uint4(w[0], w[1], w[2], w[3]);
        }
    };

    const int nA = wn + r16, nB = wn + 16 + r16;
    const char* pA = (const char*)Bs + (size_t)nA * 512;
    const char* pB = (const char*)Bs + (size_t)nB * 512;
    const int xA = nA >> 3, xB = nB >> 3;

    load_tile(0);

    for (int t = 0; t < T; t++) {
        asm volatile("" ::: "memory");
        __builtin_amdgcn_s_barrier();            // A: all waves done reading Bs
        asm volatile("" ::: "memory");
        __builtin_amdgcn_sched_barrier(0);

        write_tile();                            // compiler waits pf's vmcnt
        if (t + 1 < T) load_tile(t + 1);         // prefetch under compute

        asm volatile("s_waitcnt lgkmcnt(0)" ::: "memory");  // my writes landed
        __builtin_amdgcn_s_barrier();            // B: Bs fully written
        asm volatile("" ::: "memory");
        __builtin_amdgcn_sched_barrier(0);

        f32x4 acc[2][2];
#pragma unroll
        for (int i = 0; i < 2; i++)
#pragma unroll
            for (int j = 0; j < 2; j++) acc[i][j] = (f32x4){0.f, 0.f, 0.f, 0.f};

#pragma unroll
        for (int ks = 0; ks < 6; ks++) {
            const int kb0 = ks * 4 + quad;
            bf16x8 b0 = *(const bf16x8*)(pA + ((kb0 ^ xA) << 4));
            bf16x8 b1 = *(const bf16x8*)(pB + ((kb0 ^ xB) << 4));
            acc[0][0] = __builtin_amdgcn_mfma_f32_16x16x32_bf16(aReg[ks][0], b0, acc[0][0], 0, 0, 0);
            acc[1][0] = __builtin_amdgcn_mfma_f32_16x16x32_bf16(aReg[ks][1], b0, acc[1][0], 0, 0, 0);
            acc[0][1] = __builtin_amdgcn_mfma_f32_16x16x32_bf16(aReg[ks][0], b1, acc[0][1], 0, 0, 0);
            acc[1][1] = __builtin_amdgcn_mfma_f32_16x16x32_bf16(aReg[ks][1], b1, acc[1][1], 0, 0, 0);
        }

        // epilogue: C/D layout col=lane&15, row=quad*4+reg  [verified m89/m91]
        const int n0 = g * 512 + t * 64;
#pragma unroll
        for (int sm = 0; sm < 2; sm++)
#pragma unroll
            for (int sn = 0; sn < 2; sn++) {
                const int gr = m0 + wm + sm * 16 + quad * 4;
                const int gc = n0 + wn + sn * 16 + r16;
#pragma unroll
                for (int r = 0; r < 4; r++)
                    stf(Yb + (size_t)(gr + r) * N + gc, acc[sm][sn][r]);
            }
    }
}

// ============ K2: depthwise 3x3, pad 1 — LDS-tiled, vectorized ==============
// block = 32 output rows of one (b,c) plane; stage 34x128 bf16 in LDS.
__global__ __launch_bounds__(256) void dwconv3x3(
    const bf16* __restrict__ in, const float* __restrict__ wdw,
    bf16* __restrict__ out)
{
    const int plane = blockIdx.x >> 2;          // b*576 + c
    const int ybase = (blockIdx.x & 3) << 5;    // 0,32,64,96
    const int c = plane % 576;
    const bf16* ip = in + ((size_t)plane << 14);

    __shared__ unsigned short Ls[34][128];

    for (int i = threadIdx.x; i < 34 * 16; i += 256) {
        int r = i >> 4, cx = i & 15;
        int y = ybase - 1 + r;
        uint4 v = make_uint4(0u, 0u, 0u, 0u);
        if (y >= 0 && y < 128) v = ((const uint4*)(ip + ((size_t)y << 7)))[cx];
        ((uint4*)Ls[r])[cx] = v;
    }

    float w[9];
#pragma unroll
    for (int i = 0; i < 9; i++) w[i] = wdw[c * 9 + i];

    __syncthreads();

    const int lr = threadIdx.x >> 3;         // 0..31 output row
    const int c0 = (threadIdx.x & 7) << 4;   // 0,16,..,112

    float row[3][18];
#pragma unroll
    for (int r3 = 0; r3 < 3; r3++) {
        int rr = lr + r3;
        row[r3][0]  = c0 ? __uint_as_float((unsigned int)Ls[rr][c0 - 1] << 16) : 0.f;
        row[r3][17] = (c0 + 16 < 128) ? __uint_as_float((unsigned int)Ls[rr][c0 + 16] << 16) : 0.f;
        const uint4* rp = (const uint4*)&Ls[rr][c0];
        uint4 p0 = rp[0], p1 = rp[1];
        row[r3][1] = blo(p0.x); row[r3][2] = bhi(p0.x);
        row[r3][3] = blo(p0.y); row[r3][4] = bhi(p0.y);
        row[r3][5] = blo(p0.z); row[r3][6] = bhi(p0.z);
        row[r3][7] = blo(p0.w); row[r3][8] = bhi(p0.w);
        row[r3][9]  = blo(p1.x); row[r3][10] = bhi(p1.x);
        row[r3][11] = blo(p1.y); row[r3][12] = bhi(p1.y);
        row[r3][13] = blo(p1.z); row[r3][14] = bhi(p1.z);
        row[r3][15] = blo(p1.w); row[r3][16] = bhi(p1.w);
    }

    union { unsigned short s[16]; uint4 v[2]; } o;
#pragma unroll
    for (int j = 0; j < 16; j++) {
        float s = 0.f;
#pragma unroll
        for (int r3 = 0; r3 < 3; r3++)
            s += w[r3 * 3 + 0] * row[r3][j] + w[r3 * 3 + 1] * row[r3][j + 1]
               + w[r3 * 3 + 2] * row[r3][j + 2];
        o.s[j] = f2bu(s);
    }
    uint4* op = (uint4*)(out + ((size_t)plane << 14) + ((size_t)(ybase + lr) << 7) + c0);
    op[0] = o.v[0];
    op[1] = o.v[1];
}

// ============ K3: per-row inverse L2 norm (q rows then k rows) ==============
__global__ __launch_bounds__(256) void rownorm(
    const bf16* __restrict__ qkv, float* __restrict__ rn)
{
    int r = blockIdx.x;
    int which = (r >= 1536) ? 1 : 0;
    int rr = r - which * 1536;
    int b = rr / 192, c = rr % 192;
    const bf16* p = qkv + ((size_t)(b * 576 + which * 192 + c) << 14);

    float s = 0.f;
    for (int i = threadIdx.x * 8; i < HW; i += 256 * 8) {
        float v[8];
        load8(p + i, v);
#pragma unroll
        for (int j = 0; j < 8; j++) s += v[j] * v[j];
    }
#pragma unroll
    for (int off = 32; off; off >>= 1) s += __shfl_down(s, off);
    __shared__ float red[4];
    if ((threadIdx.x & 63) == 0) red[threadIdx.x >> 6] = s;
    __syncthreads();
    if (threadIdx.x == 0) {
        float t = red[0] + red[1] + red[2] + red[3];
        rn[r] = 1.0f / fmaxf(sqrtf(t), 1e-12f);
    }
}

// ============ K4: raw dot products S[bh,c,d] = sum_n q[c,n]k[d,n] ===========
__global__ __launch_bounds__(256) void attn_dots(
    const bf16* __restrict__ qkv, float* __restrict__ attn)
{
    const int bh = blockIdx.y, b = bh >> 2, h = bh & 3;
    const int n0 = blockIdx.x * 1024;
    const bf16* q  = qkv + ((size_t)(b * 576 + h * 48) << 14);
    const bf16* kp = qkv + ((size_t)(b * 576 + 192 + h * 48) << 14);

    __shared__ float qt[48][68];
    __shared__ float kt[48][68];

    const int tid = threadIdx.x;
    const int cg = tid >> 4, dg = tid & 15;

    float acc[3][3] = {{0.f, 0.f, 0.f}, {0.f, 0.f, 0.f}, {0.f, 0.f, 0.f}};

    for (int s0 = 0; s0 < 1024; s0 += 64) {
        for (int i = tid; i < 48 * 8; i += 256) {
            int rowi = i / 8, cx = (i & 7) * 8;
            size_t off = ((size_t)rowi << 14) + n0 + s0 + cx;
            float v[8];
            load8(q + off, v);
#pragma unroll
            for (int j = 0; j < 8; j++) qt[rowi][cx + j] = v[j];
            load8(kp + off, v);
#pragma unroll
            for (int j = 0; j < 8; j++) kt[rowi][cx + j] = v[j];
        }
        __syncthreads();
#pragma unroll 8
        for (int n = 0; n < 64; n++) {
            float a0 = qt[cg * 3 + 0][n], a1 = qt[cg * 3 + 1][n], a2 = qt[cg * 3 + 2][n];
            float b0 = kt[dg * 3 + 0][n], b1 = kt[dg * 3 + 1][n], b2 = kt[dg * 3 + 2][n];
            acc[0][0] += a0 * b0; acc[0][1] += a0 * b1; acc[0][2] += a0 * b2;
            acc[1][0] += a1 * b0; acc[1][1] += a1 * b1; acc[1][2] += a1 * b2;
            acc[2][0] += a2 * b0; acc[2][1] += a2 * b1; acc[2][2] += a2 * b2;
        }
        __syncthreads();
    }
#pragma unroll
    for (int i = 0; i < 3; i++)
#pragma unroll
        for (int j = 0; j < 3; j++)
            atomicAdd(&attn[(size_t)bh * 2304 + (cg * 3 + i) * 48 + dg * 3 + j],
                      acc[i][j]);
}

// ============ K5: scale by norms & temperature, softmax over d ==============
__global__ __launch_bounds__(64) void softmax48(
    float* __restrict__ attn, const float* __restrict__ rn,
    const float* __restrict__ temp)
{
    int bh = blockIdx.x, b = bh >> 2, h = bh & 3;
    int c = threadIdx.x;
    if (c >= 48) return;
    float t = temp[h];
    float iq = rn[b * 192 + h * 48 + c];
    const float* ik = rn + 1536 + b * 192 + h * 48;
    float* row = attn + (size_t)bh * 2304 + c * 48;

    float v[48];
    float mx = -1e30f;
#pragma unroll
    for (int d = 0; d < 48; d++) {
        v[d] = row[d] * iq * ik[d] * t;
        mx = fmaxf(mx, v[d]);
    }
    float s = 0.f;
#pragma unroll
    for (int d = 0; d < 48; d++) {
        v[d] = expf(v[d] - mx);
        s += v[d];
    }
    float inv = 1.0f / s;
#pragma unroll
    for (int d = 0; d < 48; d++) row[d] = v[d] * inv;
}

// ============ K6: out[c,n] = sum_d attn[c,d] * v[d,n] =======================
__global__ __launch_bounds__(256) void attn_v(
    const float* __restrict__ attn, const bf16* __restrict__ qkv,
    bf16* __restrict__ outb)
{
    int bh = blockIdx.y, b = bh >> 2, h = bh & 3;
    int n = blockIdx.x * 256 + threadIdx.x;

    __shared__ float A[48 * 48];
    for (int i = threadIdx.x; i < 2304; i += 256) A[i] = attn[(size_t)bh * 2304 + i];
    __syncthreads();

    const bf16* v = qkv + ((size_t)(b * 576 + 384 + h * 48) << 14) + n;
    float acc[48];
#pragma unroll
    for (int c = 0; c < 48; c++) acc[c] = 0.f;

    for (int d = 0; d < 48; d++) {
        float vd = b2f(v[(size_t)d << 14]);
#pragma unroll
        for (int c = 0; c < 48; c++) acc[c] += A[c * 48 + d] * vd;
    }
    bf16* o = outb + ((size_t)(b * 192 + h * 48) << 14) + n;
#pragma unroll
    for (int c = 0; c < 48; c++) o[(size_t)c << 14] = f2b(acc[c]);
}

// ============================================================================
extern "C" void kernel_launch(void* const* d_in, const int* in_sizes, int n_in,
                              void* d_out, int out_size, void* d_ws, size_t ws_size,
                              hipStream_t stream)
{
    const float* x      = (const float*)d_in[0];
    const float* qkv_w  = (const float*)d_in[1];
    const float* dw_w   = (const float*)d_in[2];
    const float* proj_w = (const float*)d_in[3];
    const float* temp   = (const float*)d_in[4];
    float* out = (float*)d_out;

    char* ws = (char*)d_ws;
    const size_t qkvBytes = (size_t)8 * 576 * HW * sizeof(bf16);  // 150,994,944 B
    bf16*  qkv0 = (bf16*)ws;                                  // pre-dw qkv
    bf16*  qkv1 = (bf16*)(ws + qkvBytes);                     // post-dw qkv
    float* attn = (float*)(ws + 2 * qkvBytes);                // 32*48*48 f32
    float* rn   = (float*)(ws + 2 * qkvBytes + (size_t)32 * 2304 * sizeof(float));
    bf16*  aout = qkv0;  // attn output reuses qkv0 region (50 MB < 151 MB)

    // 1) qkv 1x1 conv (MFMA): (576x192) @ (192x16384) per batch
    //    grid = MB(9) * 32 n-groups * 8 batches; batch = blockIdx%8 = XCD
    gemm_mfma<float, bf16><<<dim3(9 * 32 * 8), 256, 0, stream>>>(
        qkv_w, x, qkv0, 9);
    // 2) depthwise 3x3 (LDS-tiled)
    dwconv3x3<<<dim3(8 * 576 * 4), 256, 0, stream>>>(qkv0, dw_w, qkv1);
    // 3) inverse L2 norms for q and k rows
    rownorm<<<dim3(3072), 256, 0, stream>>>(qkv1, rn);
    // 4) attention dots (f32 atomics into zeroed buffer)
    hipMemsetAsync(attn, 0, (size_t)32 * 2304 * sizeof(float), stream);
    attn_dots<<<dim3(16, 32), 256, 0, stream>>>(qkv1, attn);
    // 5) scale + softmax
    softmax48<<<dim3(32), 64, 0, stream>>>(attn, rn, temp);
    // 6) attn @ v
    attn_v<<<dim3(64, 32), 256, 0, stream>>>(attn, qkv1, aout);
    // 7) proj 1x1 conv (MFMA): (192x192) @ (192x16384) per batch
    gemm_mfma<bf16, float><<<dim3(3 * 32 * 8), 256, 0, stream>>>(
        proj_w, aout, out, 3);
}

// Round 3
// 571.477 us; speedup vs baseline: 1.1902x; 1.1902x over previous
//
#include <hip/hip_runtime.h>
#include <hip/hip_bf16.h>

typedef __hip_bfloat16 bf16;
typedef __attribute__((ext_vector_type(8))) __bf16 bf16x8;
typedef __attribute__((ext_vector_type(4))) float f32x4;
typedef unsigned int u32;

#define HW 16384

static __device__ __forceinline__ float b2f(bf16 v) { return __bfloat162float(v); }
static __device__ __forceinline__ bf16 f2b(float v) { return __float2bfloat16(v); }
static __device__ __forceinline__ float blo(unsigned int w) {
    return __uint_as_float(w << 16);
}
static __device__ __forceinline__ float bhi(unsigned int w) {
    return __uint_as_float(w & 0xffff0000u);
}
static __device__ __forceinline__ unsigned short f2bu(float v) {
    union { bf16 b; unsigned short u; } c; c.b = f2b(v); return c.u;
}

static __device__ __forceinline__ void stf(float* p, float v) { *p = v; }
static __device__ __forceinline__ void stf(bf16* p, float v)  { *p = f2b(v); }

// load 8 consecutive values as f32 (16B- or 32B-vectorized)
static __device__ __forceinline__ void load8(const float* p, float* v) {
    const float4* q = (const float4*)p;
    float4 a = q[0], b = q[1];
    v[0] = a.x; v[1] = a.y; v[2] = a.z; v[3] = a.w;
    v[4] = b.x; v[5] = b.y; v[6] = b.z; v[7] = b.w;
}
static __device__ __forceinline__ void load8(const bf16* p, float* v) {
    uint4 u = *(const uint4*)p;
    v[0] = blo(u.x); v[1] = bhi(u.x); v[2] = blo(u.y); v[3] = bhi(u.y);
    v[4] = blo(u.z); v[5] = bhi(u.z); v[6] = blo(u.w); v[7] = bhi(u.w);
}

// ============ K1/K7: MFMA GEMM Y[b] = W(MxK=192,f32) @ X[b](192xN) ==========
// R0 tile shape (64x64, 4 waves of 32x32, mfma 16x16x32) + pipelining:
//  - A (weights) register-resident per wave: aReg[6][2] = 48 VGPR, loaded
//    once per block (L2-resident W). No A staging, no A barriers.
//  - B double-buffered in R0's swizzled layout Bs[buf][n][40] (10 KB LDS):
//    col = ((k>>3 ^ n>>3)&3)*8 + (k&7); write 2-way, read conflict-free.
//  - Block covers 4 n-tiles x 6 k-steps = 24 flattened iters (full unroll,
//    compile-time indices). Depth-2 register prefetch: tile it+2 issued at
//    iter it into pf[it&1], packed->LDS at iter it+1, consumed at it+2.
//  - ONE raw s_barrier per iter with lgkmcnt(0) only (T4: vmcnt never
//    drained in-loop; prefetch loads fly across barriers). __syncthreads
//    would drain vmcnt(0) and re-serialize on HBM latency.
// Race ledger: iter it reads buf[it&1] (written it-1 + lgkm + barrier);
// writes buf[(it+1)&1] whose prior readers (it-1) passed that barrier.
// Grid: blockIdx%8 = XCD = batch; mb fastest -> MB blocks sharing an X
// panel co-resident on one XCD's L2.
template <typename TX, typename TY>
__global__ __launch_bounds__(256) void gemm_mfma(
    const float* __restrict__ Wm, const TX* __restrict__ X,
    TY* __restrict__ Y, int MB)
{
    constexpr int K = 192, N = HW;
    constexpr int NIT = 24;              // 4 n-tiles * 6 k-steps

    const int b    = blockIdx.x & 7;
    const int slot = blockIdx.x >> 3;
    const int mb   = slot % MB;
    const int nb4  = slot / MB;          // 0..63, group of 4 n-tiles
    const int m0   = mb * 64;
    const int nbase = nb4 * 256;

    const TX* Xb = X + (size_t)b * K * N;
    TY* Yb = Y + (size_t)b * (MB * 64) * N;

    __shared__ __bf16 Bs[2][64][40];     // 2 x 5120 B

    const int tid  = threadIdx.x;
    const int lane = tid & 63, wave = tid >> 6;
    const int wm = (wave & 1) * 32, wn = (wave >> 1) * 32;
    const int r16 = lane & 15, quad = lane >> 4;

    // ---- A (weights) -> registers, once per block ----
    bf16x8 aReg[6][2];
#pragma unroll
    for (int ks = 0; ks < 6; ks++)
#pragma unroll
        for (int h = 0; h < 2; h++) {
            const float* ap = Wm + (size_t)(m0 + wm + h * 16 + r16) * K
                            + ks * 32 + quad * 8;
            float4 f0 = ((const float4*)ap)[0];
            float4 f1 = ((const float4*)ap)[1];
            bf16x8 fr;
            fr[0] = (__bf16)f0.x; fr[1] = (__bf16)f0.y;
            fr[2] = (__bf16)f0.z; fr[3] = (__bf16)f0.w;
            fr[4] = (__bf16)f1.x; fr[5] = (__bf16)f1.y;
            fr[6] = (__bf16)f1.z; fr[7] = (__bf16)f1.w;
            aReg[ks][h] = fr;
        }

    // staging role: thread -> (kk = k-row 0..31, n8 = 8-col block)
    const int kk = tid >> 3;             // 0..31
    const int n8 = (tid & 7) * 8;        // 0,8,..,56
    const int kb3 = kk >> 3, ki = kk & 7;

    uint4 pf[2][2];                      // [parity][quad-words]; idx compile-time

    auto load_tile = [&](int it, int par) {
        const TX* src = Xb + (size_t)((it % 6) * 32 + kk) * N
                      + nbase + (it / 6) * 64 + n8;
        if constexpr (sizeof(TX) == 4) {
            pf[par][0] = ((const uint4*)src)[0];
            pf[par][1] = ((const uint4*)src)[1];
        } else {
            pf[par][0] = *(const uint4*)src;
        }
    };

    auto stage_write = [&](int par, int p) {
#pragma unroll
        for (int j = 0; j < 8; j++) {
            __bf16 bv;
            if constexpr (sizeof(TX) == 4) {
                bv = (__bf16)(((const float*)&pf[par][0])[j]);
            } else {
                bv = ((const __bf16*)&pf[par][0])[j];
            }
            int n = n8 + j;
            int col = (((kb3 ^ (n >> 3)) & 3) << 3) | ki;
            Bs[p][n][col] = bv;
        }
    };

    const int nA = wn + r16, nB = wn + 16 + r16;
    const int xA = (nA >> 3) & 3, xB = (nB >> 3) & 3;

    f32x4 acc[2][2];
#pragma unroll
    for (int i = 0; i < 2; i++)
#pragma unroll
        for (int j = 0; j < 2; j++) acc[i][j] = (f32x4){0.f, 0.f, 0.f, 0.f};

    // prologue: tiles 0,1 in flight; tile 0 packed into buf 0
    load_tile(0, 0);
    load_tile(1, 1);
    stage_write(0, 0);
    asm volatile("s_waitcnt lgkmcnt(0)" ::: "memory");
    __builtin_amdgcn_s_barrier();
    __builtin_amdgcn_sched_barrier(0);

#pragma unroll
    for (int it = 0; it < NIT; it++) {
        const int p = it & 1;
        const int ks = it % 6;

        // issue tile it+2 early (lands in pf[it&1], free since pack at it-1)
        if (it + 2 < NIT) load_tile(it + 2, p);
        __builtin_amdgcn_sched_barrier(0);

        // compute from buf[p]
        bf16x8 b0 = *(const bf16x8*)&Bs[p][nA][((quad ^ xA) & 3) << 3];
        bf16x8 b1 = *(const bf16x8*)&Bs[p][nB][((quad ^ xB) & 3) << 3];
        acc[0][0] = __builtin_amdgcn_mfma_f32_16x16x32_bf16(aReg[ks][0], b0, acc[0][0], 0, 0, 0);
        acc[0][1] = __builtin_amdgcn_mfma_f32_16x16x32_bf16(aReg[ks][0], b1, acc[0][1], 0, 0, 0);
        acc[1][0] = __builtin_amdgcn_mfma_f32_16x16x32_bf16(aReg[ks][1], b0, acc[1][0], 0, 0, 0);
        acc[1][1] = __builtin_amdgcn_mfma_f32_16x16x32_bf16(aReg[ks][1], b1, acc[1][1], 0, 0, 0);

        // pack tile it+1 (waits its vmcnt via reg deps) into buf[p^1]
        if (it + 1 < NIT) stage_write((it + 1) & 1, p ^ 1);

        asm volatile("s_waitcnt lgkmcnt(0)" ::: "memory");
        __builtin_amdgcn_s_barrier();
        __builtin_amdgcn_sched_barrier(0);

        // end of an n-tile: store + reset acc
        if (ks == 5) {
            const int n0 = nbase + (it / 6) * 64;
#pragma unroll
            for (int sm = 0; sm < 2; sm++)
#pragma unroll
                for (int sn = 0; sn < 2; sn++) {
                    const int gr = m0 + wm + sm * 16 + quad * 4;
                    const int gc = n0 + wn + sn * 16 + r16;
#pragma unroll
                    for (int r = 0; r < 4; r++)
                        stf(Yb + (size_t)(gr + r) * N + gc, acc[sm][sn][r]);
                    acc[sm][sn] = (f32x4){0.f, 0.f, 0.f, 0.f};
                }
        }
    }
}

// ============ K2: depthwise 3x3, pad 1 — LDS-tiled, vectorized ==============
// block = 32 output rows of one (b,c) plane; stage 34x128 bf16 in LDS.
__global__ __launch_bounds__(256) void dwconv3x3(
    const bf16* __restrict__ in, const float* __restrict__ wdw,
    bf16* __restrict__ out)
{
    const int plane = blockIdx.x >> 2;          // b*576 + c
    const int ybase = (blockIdx.x & 3) << 5;    // 0,32,64,96
    const int c = plane % 576;
    const bf16* ip = in + ((size_t)plane << 14);

    __shared__ unsigned short Ls[34][128];

    for (int i = threadIdx.x; i < 34 * 16; i += 256) {
        int r = i >> 4, cx = i & 15;
        int y = ybase - 1 + r;
        uint4 v = make_uint4(0u, 0u, 0u, 0u);
        if (y >= 0 && y < 128) v = ((const uint4*)(ip + ((size_t)y << 7)))[cx];
        ((uint4*)Ls[r])[cx] = v;
    }

    float w[9];
#pragma unroll
    for (int i = 0; i < 9; i++) w[i] = wdw[c * 9 + i];

    __syncthreads();

    const int lr = threadIdx.x >> 3;         // 0..31 output row
    const int c0 = (threadIdx.x & 7) << 4;   // 0,16,..,112

    float row[3][18];
#pragma unroll
    for (int r3 = 0; r3 < 3; r3++) {
        int rr = lr + r3;
        row[r3][0]  = c0 ? __uint_as_float((unsigned int)Ls[rr][c0 - 1] << 16) : 0.f;
        row[r3][17] = (c0 + 16 < 128) ? __uint_as_float((unsigned int)Ls[rr][c0 + 16] << 16) : 0.f;
        const uint4* rp = (const uint4*)&Ls[rr][c0];
        uint4 p0 = rp[0], p1 = rp[1];
        row[r3][1] = blo(p0.x); row[r3][2] = bhi(p0.x);
        row[r3][3] = blo(p0.y); row[r3][4] = bhi(p0.y);
        row[r3][5] = blo(p0.z); row[r3][6] = bhi(p0.z);
        row[r3][7] = blo(p0.w); row[r3][8] = bhi(p0.w);
        row[r3][9]  = blo(p1.x); row[r3][10] = bhi(p1.x);
        row[r3][11] = blo(p1.y); row[r3][12] = bhi(p1.y);
        row[r3][13] = blo(p1.z); row[r3][14] = bhi(p1.z);
        row[r3][15] = blo(p1.w); row[r3][16] = bhi(p1.w);
    }

    union { unsigned short s[16]; uint4 v[2]; } o;
#pragma unroll
    for (int j = 0; j < 16; j++) {
        float s = 0.f;
#pragma unroll
        for (int r3 = 0; r3 < 3; r3++)
            s += w[r3 * 3 + 0] * row[r3][j] + w[r3 * 3 + 1] * row[r3][j + 1]
               + w[r3 * 3 + 2] * row[r3][j + 2];
        o.s[j] = f2bu(s);
    }
    uint4* op = (uint4*)(out + ((size_t)plane << 14) + ((size_t)(ybase + lr) << 7) + c0);
    op[0] = o.v[0];
    op[1] = o.v[1];
}

// ============ K3: per-row inverse L2 norm (q rows then k rows) ==============
__global__ __launch_bounds__(256) void rownorm(
    const bf16* __restrict__ qkv, float* __restrict__ rn)
{
    int r = blockIdx.x;
    int which = (r >= 1536) ? 1 : 0;
    int rr = r - which * 1536;
    int b = rr / 192, c = rr % 192;
    const bf16* p = qkv + ((size_t)(b * 576 + which * 192 + c) << 14);

    float s = 0.f;
    for (int i = threadIdx.x * 8; i < HW; i += 256 * 8) {
        float v[8];
        load8(p + i, v);
#pragma unroll
        for (int j = 0; j < 8; j++) s += v[j] * v[j];
    }
#pragma unroll
    for (int off = 32; off; off >>= 1) s += __shfl_down(s, off);
    __shared__ float red[4];
    if ((threadIdx.x & 63) == 0) red[threadIdx.x >> 6] = s;
    __syncthreads();
    if (threadIdx.x == 0) {
        float t = red[0] + red[1] + red[2] + red[3];
        rn[r] = 1.0f / fmaxf(sqrtf(t), 1e-12f);
    }
}

// ============ K4: raw dot products S[bh,c,d] = sum_n q[c,n]k[d,n] ===========
__global__ __launch_bounds__(256) void attn_dots(
    const bf16* __restrict__ qkv, float* __restrict__ attn)
{
    const int bh = blockIdx.y, b = bh >> 2, h = bh & 3;
    const int n0 = blockIdx.x * 1024;
    const bf16* q  = qkv + ((size_t)(b * 576 + h * 48) << 14);
    const bf16* kp = qkv + ((size_t)(b * 576 + 192 + h * 48) << 14);

    __shared__ float qt[48][68];
    __shared__ float kt[48][68];

    const int tid = threadIdx.x;
    const int cg = tid >> 4, dg = tid & 15;

    float acc[3][3] = {{0.f, 0.f, 0.f}, {0.f, 0.f, 0.f}, {0.f, 0.f, 0.f}};

    for (int s0 = 0; s0 < 1024; s0 += 64) {
        for (int i = tid; i < 48 * 8; i += 256) {
            int rowi = i / 8, cx = (i & 7) * 8;
            size_t off = ((size_t)rowi << 14) + n0 + s0 + cx;
            float v[8];
            load8(q + off, v);
#pragma unroll
            for (int j = 0; j < 8; j++) qt[rowi][cx + j] = v[j];
            load8(kp + off, v);
#pragma unroll
            for (int j = 0; j < 8; j++) kt[rowi][cx + j] = v[j];
        }
        __syncthreads();
#pragma unroll 8
        for (int n = 0; n < 64; n++) {
            float a0 = qt[cg * 3 + 0][n], a1 = qt[cg * 3 + 1][n], a2 = qt[cg * 3 + 2][n];
            float b0 = kt[dg * 3 + 0][n], b1 = kt[dg * 3 + 1][n], b2 = kt[dg * 3 + 2][n];
            acc[0][0] += a0 * b0; acc[0][1] += a0 * b1; acc[0][2] += a0 * b2;
            acc[1][0] += a1 * b0; acc[1][1] += a1 * b1; acc[1][2] += a1 * b2;
            acc[2][0] += a2 * b0; acc[2][1] += a2 * b1; acc[2][2] += a2 * b2;
        }
        __syncthreads();
    }
#pragma unroll
    for (int i = 0; i < 3; i++)
#pragma unroll
        for (int j = 0; j < 3; j++)
            atomicAdd(&attn[(size_t)bh * 2304 + (cg * 3 + i) * 48 + dg * 3 + j],
                      acc[i][j]);
}

// ============ K5: scale by norms & temperature, softmax over d ==============
__global__ __launch_bounds__(64) void softmax48(
    float* __restrict__ attn, const float* __restrict__ rn,
    const float* __restrict__ temp)
{
    int bh = blockIdx.x, b = bh >> 2, h = bh & 3;
    int c = threadIdx.x;
    if (c >= 48) return;
    float t = temp[h];
    float iq = rn[b * 192 + h * 48 + c];
    const float* ik = rn + 1536 + b * 192 + h * 48;
    float* row = attn + (size_t)bh * 2304 + c * 48;

    float v[48];
    float mx = -1e30f;
#pragma unroll
    for (int d = 0; d < 48; d++) {
        v[d] = row[d] * iq * ik[d] * t;
        mx = fmaxf(mx, v[d]);
    }
    float s = 0.f;
#pragma unroll
    for (int d = 0; d < 48; d++) {
        v[d] = expf(v[d] - mx);
        s += v[d];
    }
    float inv = 1.0f / s;
#pragma unroll
    for (int d = 0; d < 48; d++) row[d] = v[d] * inv;
}

// ============ K6: out[c,n] = sum_d attn[c,d] * v[d,n] =======================
__global__ __launch_bounds__(256) void attn_v(
    const float* __restrict__ attn, const bf16* __restrict__ qkv,
    bf16* __restrict__ outb)
{
    int bh = blockIdx.y, b = bh >> 2, h = bh & 3;
    int n = blockIdx.x * 256 + threadIdx.x;

    __shared__ float A[48 * 48];
    for (int i = threadIdx.x; i < 2304; i += 256) A[i] = attn[(size_t)bh * 2304 + i];
    __syncthreads();

    const bf16* v = qkv + ((size_t)(b * 576 + 384 + h * 48) << 14) + n;
    float acc[48];
#pragma unroll
    for (int c = 0; c < 48; c++) acc[c] = 0.f;

    for (int d = 0; d < 48; d++) {
        float vd = b2f(v[(size_t)d << 14]);
#pragma unroll
        for (int c = 0; c < 48; c++) acc[c] += A[c * 48 + d] * vd;
    }
    bf16* o = outb + ((size_t)(b * 192 + h * 48) << 14) + n;
#pragma unroll
    for (int c = 0; c < 48; c++) o[(size_t)c << 14] = f2b(acc[c]);
}

// ============================================================================
extern "C" void kernel_launch(void* const* d_in, const int* in_sizes, int n_in,
                              void* d_out, int out_size, void* d_ws, size_t ws_size,
                              hipStream_t stream)
{
    const float* x      = (const float*)d_in[0];
    const float* qkv_w  = (const float*)d_in[1];
    const float* dw_w   = (const float*)d_in[2];
    const float* proj_w = (const float*)d_in[3];
    const float* temp   = (const float*)d_in[4];
    float* out = (float*)d_out;

    char* ws = (char*)d_ws;
    const size_t qkvBytes = (size_t)8 * 576 * HW * sizeof(bf16);  // 150,994,944 B
    bf16*  qkv0 = (bf16*)ws;                                  // pre-dw qkv
    bf16*  qkv1 = (bf16*)(ws + qkvBytes);                     // post-dw qkv
    float* attn = (float*)(ws + 2 * qkvBytes);                // 32*48*48 f32
    float* rn   = (float*)(ws + 2 * qkvBytes + (size_t)32 * 2304 * sizeof(float));
    bf16*  aout = qkv0;  // attn output reuses qkv0 region (50 MB < 151 MB)

    // 1) qkv 1x1 conv (MFMA): (576x192) @ (192x16384) per batch
    //    grid = 8 XCD-batches * 9 mb * 64 n-groups (4 tiles each)
    gemm_mfma<float, bf16><<<dim3(8 * 9 * 64), 256, 0, stream>>>(
        qkv_w, x, qkv0, 9);
    // 2) depthwise 3x3 (LDS-tiled)
    dwconv3x3<<<dim3(8 * 576 * 4), 256, 0, stream>>>(qkv0, dw_w, qkv1);
    // 3) inverse L2 norms for q and k rows
    rownorm<<<dim3(3072), 256, 0, stream>>>(qkv1, rn);
    // 4) attention dots (f32 atomics into zeroed buffer)
    hipMemsetAsync(attn, 0, (size_t)32 * 2304 * sizeof(float), stream);
    attn_dots<<<dim3(16, 32), 256, 0, stream>>>(qkv1, attn);
    // 5) scale + softmax
    softmax48<<<dim3(32), 64, 0, stream>>>(attn, rn, temp);
    // 6) attn @ v
    attn_v<<<dim3(64, 32), 256, 0, stream>>>(attn, qkv1, aout);
    // 7) proj 1x1 conv (MFMA): (192x192) @ (192x16384) per batch
    gemm_mfma<bf16, float><<<dim3(8 * 3 * 64), 256, 0, stream>>>(
        proj_w, aout, out, 3);
}